// Round 5
// baseline (374.927 us; speedup 1.0000x reference)
//
#include <hip/hip_runtime.h>
#include <cstdint>
#include <cstddef>

// Problem constants (from reference)
#define NN 50000
#define NE 800000
#define FIN 256
#define HD 128
#define NEG_SLOPE 0.2f

// CSR-build binning parameters
#define NBK 196          // buckets of 256 nodes: ceil(50000/256)
#define NCH 98           // edge chunks
#define CHUNK 8192       // edges per chunk (98*8192 >= 800000)

typedef short s16x8 __attribute__((ext_vector_type(8)));   // 8 bf16 (4 VGPRs)
typedef float f32x4 __attribute__((ext_vector_type(4)));   // MFMA accumulator

__device__ inline ushort f2bf(float f) {                   // fp32 -> bf16 RTN-even
    uint32_t u = __float_as_uint(f);
    u += 0x7FFFu + ((u >> 16) & 1u);
    return (ushort)(u >> 16);
}
__device__ inline float bf2f(ushort h) {
    return __uint_as_float(((uint32_t)h) << 16);
}

// ------------------------------------------------------------- CSR build
// bucket = dst >> 8. No global atomics anywhere.

__global__ __launch_bounds__(1024) void k_bhist(const int* __restrict__ dst,
                                                int* __restrict__ bhist) {
    __shared__ int hist[NBK];
    const int tid = threadIdx.x, blk = blockIdx.x;
    if (tid < NBK) hist[tid] = 0;
    __syncthreads();
    const int e0 = blk * CHUNK;
    #pragma unroll
    for (int u = 0; u < CHUNK / 1024; ++u) {
        int e = e0 + u * 1024 + tid;
        if (e < NE) atomicAdd(&hist[dst[e] >> 8], 1);
    }
    __syncthreads();
    if (tid < NBK) bhist[blk * NBK + tid] = hist[tid];
}

__global__ __launch_bounds__(256) void k_bscan(int* __restrict__ bhist,
                                               int* __restrict__ bbeg,
                                               int* __restrict__ row_ptr) {
    __shared__ int wsum[4];
    const int tid = threadIdx.x;
    int tot = 0;
    if (tid < NBK) {
        for (int c = 0; c < NCH; ++c) {           // coalesced across tid
            int t = bhist[c * NBK + tid];
            bhist[c * NBK + tid] = tot;           // per-bucket chunk prefix
            tot += t;
        }
    }
    const int lane = tid & 63, wid = tid >> 6;
    int x = tot;
    #pragma unroll
    for (int o = 1; o < 64; o <<= 1) {
        int t = __shfl_up(x, o);
        if (lane >= o) x += t;
    }
    if (lane == 63) wsum[wid] = x;
    __syncthreads();
    int wo = 0;
    for (int k = 0; k < wid; ++k) wo += wsum[k];
    const int excl = x - tot + wo;                // bucket start offset
    if (tid < NBK) bbeg[tid] = excl;
    if (tid == 0) { bbeg[NBK] = NE; row_ptr[NN] = NE; }
    __syncthreads();
    if (tid < NBK)
        for (int c = 0; c < NCH; ++c) bhist[c * NBK + tid] += excl;
}

__global__ __launch_bounds__(1024) void k_binscatter(const int* __restrict__ src,
                                                     const int* __restrict__ dst,
                                                     const float* __restrict__ ew,
                                                     const int* __restrict__ bhist,
                                                     uint2* __restrict__ epk) {
    __shared__ int base[NBK];
    __shared__ int lcur[NBK];
    const int tid = threadIdx.x, blk = blockIdx.x;
    if (tid < NBK) { base[tid] = bhist[blk * NBK + tid]; lcur[tid] = 0; }
    __syncthreads();
    const int e0 = blk * CHUNK;
    #pragma unroll
    for (int u = 0; u < CHUNK / 1024; ++u) {
        int e = e0 + u * 1024 + tid;
        if (e < NE) {
            int d = dst[e];
            int s = src[e];
            float w = ew[e];
            int b = d >> 8;
            int pos = base[b] + atomicAdd(&lcur[b], 1);   // LDS atomic only
            epk[pos] = make_uint2((uint32_t)s | ((uint32_t)(d & 255) << 16),
                                  __float_as_uint(w));
        }
    }
}

__global__ __launch_bounds__(256) void k_build(const uint2* __restrict__ epk,
                                               const int* __restrict__ bbeg,
                                               int* __restrict__ row_ptr,
                                               int* __restrict__ col,
                                               float* __restrict__ wsrt) {
    __shared__ int cnt[256];
    __shared__ int cur[256];
    __shared__ int wsum[4];
    const int tid = threadIdx.x, b = blockIdx.x;
    const int n0 = b << 8;
    const int ebeg = bbeg[b], eend = bbeg[b + 1];
    cnt[tid] = 0;
    __syncthreads();
    for (int e = ebeg + tid; e < eend; e += 256)
        atomicAdd(&cnt[(epk[e].x >> 16) & 255], 1);
    __syncthreads();
    const int v = cnt[tid];
    const int lane = tid & 63, wid = tid >> 6;
    int x = v;
    #pragma unroll
    for (int o = 1; o < 64; o <<= 1) {
        int t = __shfl_up(x, o);
        if (lane >= o) x += t;
    }
    if (lane == 63) wsum[wid] = x;
    __syncthreads();
    int wo = 0;
    for (int k = 0; k < wid; ++k) wo += wsum[k];
    const int excl = ebeg + x - v + wo;           // node segment start
    if (n0 + tid < NN) row_ptr[n0 + tid] = excl;
    cur[tid] = excl;
    __syncthreads();
    for (int e = ebeg + tid; e < eend; e += 256) {
        uint2 p = epk[e];
        int dl = (p.x >> 16) & 255;
        int pos = atomicAdd(&cur[dl], 1);
        col[pos]  = (int)(p.x & 0xFFFFu);
        wsrt[pos] = __uint_as_float(p.y);
    }
}

// -------------------------------------------- weight transpose + bf16 split
// W [K][HD] fp32 row-major -> Th/Tl [HD][K] bf16 (hi + residual-lo)

__global__ void k_split(const float* __restrict__ W, ushort* __restrict__ Th,
                        ushort* __restrict__ Tl, int K) {
    int idx = blockIdx.x * blockDim.x + threadIdx.x;   // = n*K + k
    if (idx >= K * HD) return;
    int n = idx / K, k = idx - n * K;
    float f = W[(size_t)k * HD + n];
    ushort hi = f2bf(f);
    Th[idx] = hi;
    Tl[idx] = f2bf(f - bf2f(hi));
}

// ----------------------------------------------------- MFMA split-bf16 GEMM
// Barrier-free, LDS-free: one wave per 16-row x 128-col output tile.
// A frag loaded per-lane directly from global fp32 (row = lane&15,
// k = (lane>>4)*8..+8 matches the 16x16x32 A layout), split to hi/lo bf16
// in registers. B^T hi/lo frags straight from global (L1/L2-resident).
// D = Ahi*Bhi + Ahi*Blo + Alo*Bhi  (~fp32 accuracy).
// Grid: M/64 blocks x 4 waves; no __syncthreads anywhere.

template <int K, bool ATT>
__global__ __launch_bounds__(256) void k_gemm_mfma(
    const float*  __restrict__ A,
    const ushort* __restrict__ Bh,     // [HD][K]
    const ushort* __restrict__ Bl,     // [HD][K]
    const float*  __restrict__ bias,   // null if none
    float*        __restrict__ Cf,     // fp32 out (null if unused)
    ushort*       __restrict__ Cb,     // bf16 out (null if unused)
    const float*  __restrict__ att_s, const float* __restrict__ att_d,
    float* __restrict__ as_, float* __restrict__ ad_,
    int M)
{
    const int lane = threadIdx.x & 63;
    const int wid  = threadIdx.x >> 6;
    const int rowBase = blockIdx.x * 64 + wid * 16;
    if (rowBase >= M) return;                     // M % 16 == 0
    const int fl = lane & 15;                     // A row / B col within tile
    const int fg = lane >> 4;                     // k-group (8 elems each)

    f32x4 acc[8] = {};
    const float* arow = A + (size_t)(rowBase + fl) * K + fg * 8;

    #pragma unroll
    for (int kt = 0; kt < K / 32; ++kt) {
        float4 t0 = *reinterpret_cast<const float4*>(arow + kt * 32);
        float4 t1 = *reinterpret_cast<const float4*>(arow + kt * 32 + 4);
        float v[8] = {t0.x, t0.y, t0.z, t0.w, t1.x, t1.y, t1.z, t1.w};
        s16x8 a_h, a_l;
        #pragma unroll
        for (int u = 0; u < 8; ++u) {
            ushort h0 = f2bf(v[u]);
            a_h[u] = (short)h0;
            a_l[u] = (short)f2bf(v[u] - bf2f(h0));
        }
        #pragma unroll
        for (int ct = 0; ct < 8; ++ct) {
            const size_t boff = (size_t)(ct * 16 + fl) * K + kt * 32 + fg * 8;
            s16x8 b_h = *reinterpret_cast<const s16x8*>(Bh + boff);
            s16x8 b_l = *reinterpret_cast<const s16x8*>(Bl + boff);
            acc[ct] = __builtin_amdgcn_mfma_f32_16x16x32_bf16(a_h, b_h, acc[ct], 0, 0, 0);
            acc[ct] = __builtin_amdgcn_mfma_f32_16x16x32_bf16(a_h, b_l, acc[ct], 0, 0, 0);
            acc[ct] = __builtin_amdgcn_mfma_f32_16x16x32_bf16(a_l, b_h, acc[ct], 0, 0, 0);
        }
    }

    // epilogue: C/D layout col = ct*16 + fl, row = rowBase + fg*4 + reg
    float bval[8];
    #pragma unroll
    for (int ct = 0; ct < 8; ++ct) bval[ct] = bias ? bias[ct * 16 + fl] : 0.f;
    float asv[8], adv[8];
    if (ATT) {
        #pragma unroll
        for (int ct = 0; ct < 8; ++ct) {
            asv[ct] = att_s[ct * 16 + fl];
            adv[ct] = att_d[ct * 16 + fl];
        }
    }

    const int rbase = rowBase + fg * 4;
    #pragma unroll
    for (int r = 0; r < 4; ++r) {
        const int row = rbase + r;
        float sv = 0.f, dv = 0.f;
        #pragma unroll
        for (int ct = 0; ct < 8; ++ct) {
            float val = acc[ct][r] + bval[ct];
            if (ATT) { sv = fmaf(val, asv[ct], sv); dv = fmaf(val, adv[ct], dv); }
            if (Cf) Cf[(size_t)row * HD + ct * 16 + fl] = val;
            if (Cb) Cb[(size_t)row * HD + ct * 16 + fl] = f2bf(val);
        }
        if (ATT) {
            #pragma unroll
            for (int o = 1; o < 16; o <<= 1) {        // reduce within 16-lane group
                sv += __shfl_xor(sv, o);
                dv += __shfl_xor(dv, o);
            }
            if (fl == 0) { as_[row] = sv; ad_[row] = dv; }
        }
    }
}

// ---------------------------------------------- fused softmax-aggregation

__global__ __launch_bounds__(256) void k_agg(const ushort* __restrict__ hpb,
                                             float* __restrict__ h,
                                             const float* __restrict__ as_,
                                             const float* __restrict__ ad_,
                                             const int* __restrict__ row_ptr,
                                             const int* __restrict__ col,
                                             const float* __restrict__ wsrt,
                                             const float* __restrict__ bias,
                                             float* __restrict__ out, int mode) {
    int wave = (blockIdx.x * blockDim.x + threadIdx.x) >> 6;
    int lane = threadIdx.x & 63;
    if (wave >= NN) return;
    const int d = wave;
    const int beg = row_ptr[d], end = row_ptr[d + 1];
    const float adv = ad_[d];

    float mloc = -INFINITY;
    for (int p = beg + lane; p < end; p += 64) {
        float l = as_[col[p]] + adv;
        l = (l >= 0.f) ? l : NEG_SLOPE * l;
        mloc = fmaxf(mloc, l);
    }
    #pragma unroll
    for (int o = 32; o > 0; o >>= 1) mloc = fmaxf(mloc, __shfl_xor(mloc, o));
    const float m = (end > beg) ? mloc : 0.f;

    float ax = 0.f, ay = 0.f, dloc = 0.f;
    for (int base = beg; base < end; base += 64) {
        const int n = min(64, end - base);
        int   s = 0;
        float w = 0.f;
        if (lane < n) {
            s = col[base + lane];
            float l = as_[s] + adv;
            l = (l >= 0.f) ? l : NEG_SLOPE * l;
            w = __expf(l - m) * wsrt[base + lane];
        }
        dloc += w;

        int i = 0;
        for (; i + 3 < n; i += 4) {
            float w0 = __shfl(w, i),     w1 = __shfl(w, i + 1);
            float w2 = __shfl(w, i + 2), w3 = __shfl(w, i + 3);
            int   s0 = __shfl(s, i),     s1 = __shfl(s, i + 1);
            int   s2 = __shfl(s, i + 2), s3 = __shfl(s, i + 3);
            uint32_t p0 = *reinterpret_cast<const uint32_t*>(hpb + (size_t)s0 * HD + lane * 2);
            uint32_t p1 = *reinterpret_cast<const uint32_t*>(hpb + (size_t)s1 * HD + lane * 2);
            uint32_t p2 = *reinterpret_cast<const uint32_t*>(hpb + (size_t)s2 * HD + lane * 2);
            uint32_t p3 = *reinterpret_cast<const uint32_t*>(hpb + (size_t)s3 * HD + lane * 2);
            ax = fmaf(w0, bf2f((ushort)p0), ax); ay = fmaf(w0, bf2f((ushort)(p0 >> 16)), ay);
            ax = fmaf(w1, bf2f((ushort)p1), ax); ay = fmaf(w1, bf2f((ushort)(p1 >> 16)), ay);
            ax = fmaf(w2, bf2f((ushort)p2), ax); ay = fmaf(w2, bf2f((ushort)(p2 >> 16)), ay);
            ax = fmaf(w3, bf2f((ushort)p3), ax); ay = fmaf(w3, bf2f((ushort)(p3 >> 16)), ay);
        }
        for (; i < n; ++i) {
            float wi = __shfl(w, i);
            int   si = __shfl(s, i);
            uint32_t pv = *reinterpret_cast<const uint32_t*>(hpb + (size_t)si * HD + lane * 2);
            ax = fmaf(wi, bf2f((ushort)pv), ax); ay = fmaf(wi, bf2f((ushort)(pv >> 16)), ay);
        }
    }
    #pragma unroll
    for (int o = 32; o > 0; o >>= 1) dloc += __shfl_xor(dloc, o);

    const float inv = 1.f / (dloc + 1e-16f);
    const float r0 = ax * inv + bias[lane * 2];
    const float r1 = ay * inv + bias[lane * 2 + 1];

    const size_t off = (size_t)d * HD + lane * 2;
    if (mode == 2) {
        float2 o = *reinterpret_cast<float2*>(out + off);
        o.x = fmaxf(o.x, r0); o.y = fmaxf(o.y, r1);
        *reinterpret_cast<float2*>(out + off) = o;
    } else {
        float2 hv = *reinterpret_cast<float2*>(h + off);
        hv.x += r0; hv.y += r1;
        *reinterpret_cast<float2*>(h + off) = hv;
        if (mode == 0) {
            *reinterpret_cast<float2*>(out + off) = hv;
        } else {
            float2 o = *reinterpret_cast<float2*>(out + off);
            o.x = fmaxf(o.x, hv.x); o.y = fmaxf(o.y, hv.y);
            *reinterpret_cast<float2*>(out + off) = o;
        }
    }
}

// ---------------------------------------------------------------- launch

extern "C" void kernel_launch(void* const* d_in, const int* in_sizes, int n_in,
                              void* d_out, int out_size, void* d_ws, size_t ws_size,
                              hipStream_t stream) {
    const float* x        = (const float*)d_in[0];          // [NN][FIN]
    const int*   ei       = (const int*)d_in[1];            // [2][NE]
    const float* ew       = (const float*)d_in[2];          // [NE]
    /* d_in[3] = numNode scalar = NN */
    const float* Wlin     = (const float*)d_in[4];          // [FIN][HD]
    const float* blin     = (const float*)d_in[5];          // [HD]
    const float* Wc       = (const float*)d_in[6];          // [3][HD][HD]
    const float* att_src  = (const float*)d_in[7];          // [3][HD]
    const float* att_dst  = (const float*)d_in[8];          // [3][HD]
    const float* bias_c   = (const float*)d_in[9];          // [3][HD]
    float* out = (float*)d_out;                              // [NN][HD]

    const int* src = ei;
    const int* dst = ei + NE;

    // workspace layout (16B-aligned blocks, ~52 MB)
    char* w = (char*)d_ws;
    float*  h       = (float*)w;   w += (size_t)NN * HD * 4;
    ushort* hpb     = (ushort*)w;  w += (size_t)NN * HD * 2;
    float*  as_     = (float*)w;   w += (size_t)NN * 4;
    float*  ad_     = (float*)w;   w += (size_t)NN * 4;
    int*    row_ptr = (int*)w;     w += (size_t)(NN + 4) * 4;
    int*    col     = (int*)w;     w += (size_t)NE * 4;
    float*  wsrt    = (float*)w;   w += (size_t)NE * 4;
    uint2*  epk     = (uint2*)w;   w += (size_t)NE * 8;
    int*    bhist   = (int*)w;     w += (size_t)NCH * NBK * 4;
    int*    bbeg    = (int*)w;     w += (size_t)(NBK + 4) * 4;
    ushort* WTh     = (ushort*)w;  w += (size_t)(HD * FIN + 3 * HD * HD) * 2;
    ushort* WTl     = (ushort*)w;  w += (size_t)(HD * FIN + 3 * HD * HD) * 2;
    ushort* WlinTh = WTh,            *WlinTl = WTl;
    ushort* WcTh   = WTh + HD * FIN, *WcTl   = WTl + HD * FIN;

    const int TB = 256;
    const int nblk_w = (NN * 64 + TB - 1) / TB;      // one wave per node
    const int nblk_g = (NN + 63) / 64;               // 782 (64 rows per block)

    // ---- weight transpose + split (tiny) ----
    k_split<<<(HD * FIN + TB - 1) / TB, TB, 0, stream>>>(Wlin, WlinTh, WlinTl, FIN);
    for (int l = 0; l < 3; ++l)
        k_split<<<(HD * HD + TB - 1) / TB, TB, 0, stream>>>(
            Wc + (size_t)l * HD * HD, WcTh + (size_t)l * HD * HD,
            WcTl + (size_t)l * HD * HD, HD);

    // ---- CSR build (atomic-reservation-free binning) ----
    k_bhist<<<NCH, 1024, 0, stream>>>(dst, bhist);
    k_bscan<<<1, 256, 0, stream>>>(bhist, bbeg, row_ptr);
    k_binscatter<<<NCH, 1024, 0, stream>>>(src, dst, ew, bhist, epk);
    k_build<<<NBK, 256, 0, stream>>>(epk, bbeg, row_ptr, col, wsrt);

    // ---- input projection: h = x @ Wlin + blin (fp32 out) ----
    k_gemm_mfma<FIN, false><<<nblk_g, TB, 0, stream>>>(
        x, WlinTh, WlinTl, blin, h, nullptr, nullptr, nullptr, nullptr, nullptr, NN);

    // ---- 3 GAT layers ----
    for (int layer = 0; layer < 3; ++layer) {
        k_gemm_mfma<HD, true><<<nblk_g, TB, 0, stream>>>(
            h, WcTh + (size_t)layer * HD * HD, WcTl + (size_t)layer * HD * HD,
            nullptr, nullptr, hpb,
            att_src + layer * HD, att_dst + layer * HD, as_, ad_, NN);
        int mode = (layer == 0) ? 0 : (layer == 2 ? 2 : 1);
        k_agg<<<nblk_w, TB, 0, stream>>>(hpb, h, as_, ad_, row_ptr, col, wsrt,
                                         bias_c + layer * HD, out, mode);
    }
}

// Round 6
// 260.885 us; speedup vs baseline: 1.4371x; 1.4371x over previous
//
#include <hip/hip_runtime.h>
#include <cstdint>
#include <cstddef>

// Problem constants (from reference)
#define NN 50000
#define NE 800000
#define FIN 256
#define HD 128
#define NEG_SLOPE 0.2f

// CSR-build binning parameters
#define NBK 196          // buckets of 256 nodes: ceil(50000/256)
#define NCH 98           // edge chunks
#define CHUNK 8192       // edges per chunk (98*8192 >= 800000)

typedef short s16x8 __attribute__((ext_vector_type(8)));   // 8 bf16 (4 VGPRs)
typedef float f32x4 __attribute__((ext_vector_type(4)));   // MFMA accumulator

__device__ inline ushort f2bf(float f) {                   // fp32 -> bf16 RTN-even
    uint32_t u = __float_as_uint(f);
    u += 0x7FFFu + ((u >> 16) & 1u);
    return (ushort)(u >> 16);
}
__device__ inline float bf2f(ushort h) {
    return __uint_as_float(((uint32_t)h) << 16);
}

// ------------------------------------------------------------- CSR build
// bucket = dst >> 8. No global atomics anywhere.

__global__ __launch_bounds__(1024) void k_bhist(const int* __restrict__ dst,
                                                int* __restrict__ bhist) {
    __shared__ int hist[NBK];
    const int tid = threadIdx.x, blk = blockIdx.x;
    if (tid < NBK) hist[tid] = 0;
    __syncthreads();
    const int e0 = blk * CHUNK;
    #pragma unroll
    for (int u = 0; u < CHUNK / 1024; ++u) {
        int e = e0 + u * 1024 + tid;
        if (e < NE) atomicAdd(&hist[dst[e] >> 8], 1);
    }
    __syncthreads();
    if (tid < NBK) bhist[blk * NBK + tid] = hist[tid];
}

__global__ __launch_bounds__(256) void k_bscan(int* __restrict__ bhist,
                                               int* __restrict__ bbeg,
                                               int* __restrict__ row_ptr) {
    __shared__ int wsum[4];
    const int tid = threadIdx.x;
    int tot = 0;
    if (tid < NBK) {
        for (int c = 0; c < NCH; ++c) {           // coalesced across tid
            int t = bhist[c * NBK + tid];
            bhist[c * NBK + tid] = tot;           // per-bucket chunk prefix
            tot += t;
        }
    }
    const int lane = tid & 63, wid = tid >> 6;
    int x = tot;
    #pragma unroll
    for (int o = 1; o < 64; o <<= 1) {
        int t = __shfl_up(x, o);
        if (lane >= o) x += t;
    }
    if (lane == 63) wsum[wid] = x;
    __syncthreads();
    int wo = 0;
    for (int k = 0; k < wid; ++k) wo += wsum[k];
    const int excl = x - tot + wo;                // bucket start offset
    if (tid < NBK) bbeg[tid] = excl;
    if (tid == 0) { bbeg[NBK] = NE; row_ptr[NN] = NE; }
    __syncthreads();
    if (tid < NBK)
        for (int c = 0; c < NCH; ++c) bhist[c * NBK + tid] += excl;
}

__global__ __launch_bounds__(1024) void k_binscatter(const int* __restrict__ src,
                                                     const int* __restrict__ dst,
                                                     const float* __restrict__ ew,
                                                     const int* __restrict__ bhist,
                                                     uint2* __restrict__ epk) {
    __shared__ int base[NBK];
    __shared__ int lcur[NBK];
    const int tid = threadIdx.x, blk = blockIdx.x;
    if (tid < NBK) { base[tid] = bhist[blk * NBK + tid]; lcur[tid] = 0; }
    __syncthreads();
    const int e0 = blk * CHUNK;
    #pragma unroll
    for (int u = 0; u < CHUNK / 1024; ++u) {
        int e = e0 + u * 1024 + tid;
        if (e < NE) {
            int d = dst[e];
            int s = src[e];
            float w = ew[e];
            int b = d >> 8;
            int pos = base[b] + atomicAdd(&lcur[b], 1);   // LDS atomic only
            epk[pos] = make_uint2((uint32_t)s | ((uint32_t)(d & 255) << 16),
                                  __float_as_uint(w));
        }
    }
}

__global__ __launch_bounds__(256) void k_build(const uint2* __restrict__ epk,
                                               const int* __restrict__ bbeg,
                                               int* __restrict__ row_ptr,
                                               int* __restrict__ col,
                                               float* __restrict__ wsrt) {
    __shared__ int cnt[256];
    __shared__ int cur[256];
    __shared__ int wsum[4];
    const int tid = threadIdx.x, b = blockIdx.x;
    const int n0 = b << 8;
    const int ebeg = bbeg[b], eend = bbeg[b + 1];
    cnt[tid] = 0;
    __syncthreads();
    for (int e = ebeg + tid; e < eend; e += 256)
        atomicAdd(&cnt[(epk[e].x >> 16) & 255], 1);
    __syncthreads();
    const int v = cnt[tid];
    const int lane = tid & 63, wid = tid >> 6;
    int x = v;
    #pragma unroll
    for (int o = 1; o < 64; o <<= 1) {
        int t = __shfl_up(x, o);
        if (lane >= o) x += t;
    }
    if (lane == 63) wsum[wid] = x;
    __syncthreads();
    int wo = 0;
    for (int k = 0; k < wid; ++k) wo += wsum[k];
    const int excl = ebeg + x - v + wo;           // node segment start
    if (n0 + tid < NN) row_ptr[n0 + tid] = excl;
    cur[tid] = excl;
    __syncthreads();
    for (int e = ebeg + tid; e < eend; e += 256) {
        uint2 p = epk[e];
        int dl = (p.x >> 16) & 255;
        int pos = atomicAdd(&cur[dl], 1);
        col[pos]  = (int)(p.x & 0xFFFFu);
        wsrt[pos] = __uint_as_float(p.y);
    }
}

// -------------------------------------------- weight transpose + bf16 split
// W [K][HD] fp32 row-major -> Th/Tl [HD][K] bf16 (hi + residual-lo)

__global__ void k_split(const float* __restrict__ W, ushort* __restrict__ Th,
                        ushort* __restrict__ Tl, int K) {
    int idx = blockIdx.x * blockDim.x + threadIdx.x;   // = n*K + k
    if (idx >= K * HD) return;
    int n = idx / K, k = idx - n * K;
    float f = W[(size_t)k * HD + n];
    ushort hi = f2bf(f);
    Th[idx] = hi;
    Tl[idx] = f2bf(f - bf2f(hi));
}

// ----------------------------------------------------- MFMA split-bf16 GEMM
// C[M][128] = A[M][K] @ B[K][128] (+bias), 16x16x32 bf16 MFMA,
// D = Ahi*Bhi + Ahi*Blo + Alo*Bhi  (~fp32 accuracy).
//
// Structure (round-6): B^T hi/lo for a whole BK=128 K-tile staged ONCE into
// LDS (64 KB, XOR-swizzled 16B chunks: pos = c ^ (col&15), conflict-free on
// both the coalesced staging write and the frag read). Then a barrier-FREE
// main loop: A frags per-lane from global (independent addrs), B frags via
// ds_read_b128. Block = 4 waves x 32 rows = 128 rows; grid 391.
// K=256 restages once (3 barriers total); K=128 has exactly 1 barrier.

template <int K, bool ATT>
__global__ __launch_bounds__(256) void k_gemm_mfma(
    const float*  __restrict__ A,
    const ushort* __restrict__ Bh,     // [HD][K]
    const ushort* __restrict__ Bl,     // [HD][K]
    const float*  __restrict__ bias,   // null if none
    float*        __restrict__ Cf,     // fp32 out (null if unused)
    ushort*       __restrict__ Cb,     // bf16 out (null if unused)
    const float*  __restrict__ att_s, const float* __restrict__ att_d,
    float* __restrict__ as_, float* __restrict__ ad_,
    int M)
{
    constexpr int BK = 128;                       // K-elems per LDS tile
    constexpr int NT = K / BK;                    // 1 or 2 tiles
    __shared__ ushort Bs[32768];                  // 64 KB: hi [0..16383], lo +16384

    const int tid  = threadIdx.x;
    const int lane = tid & 63;
    const int wid  = tid >> 6;
    const int fl   = lane & 15;                   // A row / B col within frag
    const int fg   = lane >> 4;                   // k-group (8 elems)
    const int rowBase = blockIdx.x * 128 + wid * 32;

    f32x4 acc[2][8] = {};

    for (int t = 0; t < NT; ++t) {
        if (t) __syncthreads();                   // all waves done with tile t-1
        // ---- stage B tile: 2048 16B-chunks per half, coalesced reads ----
        // chunk id: col = id>>4, c = id&15; LDS pos swizzled: c ^ (col&15)
        #pragma unroll
        for (int u = 0; u < 8; ++u) {
            const int id  = u * 256 + tid;
            const int bcol = id >> 4, c = id & 15;
            const size_t g = (size_t)bcol * K + t * BK + c * 8;
            const int lidx = bcol * 128 + ((c ^ (bcol & 15)) << 3);
            *reinterpret_cast<uint4*>(&Bs[lidx]) =
                *reinterpret_cast<const uint4*>(Bh + g);
            *reinterpret_cast<uint4*>(&Bs[16384 + lidx]) =
                *reinterpret_cast<const uint4*>(Bl + g);
        }
        __syncthreads();

        // ---- barrier-free compute over the tile ----
        #pragma unroll
        for (int kt = 0; kt < BK / 32; ++kt) {
            s16x8 a_h[2], a_l[2];
            #pragma unroll
            for (int rt = 0; rt < 2; ++rt) {
                int r = rowBase + rt * 16 + fl;
                if (r >= M) r = M - 1;            // harmless clamp (stores guarded)
                const float* ap = A + (size_t)r * K + t * BK + kt * 32 + fg * 8;
                float4 t0 = *reinterpret_cast<const float4*>(ap);
                float4 t1 = *reinterpret_cast<const float4*>(ap + 4);
                float v[8] = {t0.x, t0.y, t0.z, t0.w, t1.x, t1.y, t1.z, t1.w};
                #pragma unroll
                for (int u = 0; u < 8; ++u) {
                    ushort h0 = f2bf(v[u]);
                    a_h[rt][u] = (short)h0;
                    a_l[rt][u] = (short)f2bf(v[u] - bf2f(h0));
                }
            }
            #pragma unroll
            for (int ct = 0; ct < 8; ++ct) {
                const int lidx = (ct * 16 + fl) * 128 + (((kt * 4 + fg) ^ fl) << 3);
                s16x8 b_h = *reinterpret_cast<const s16x8*>(&Bs[lidx]);
                s16x8 b_l = *reinterpret_cast<const s16x8*>(&Bs[16384 + lidx]);
                #pragma unroll
                for (int rt = 0; rt < 2; ++rt) {
                    acc[rt][ct] = __builtin_amdgcn_mfma_f32_16x16x32_bf16(a_h[rt], b_h, acc[rt][ct], 0, 0, 0);
                    acc[rt][ct] = __builtin_amdgcn_mfma_f32_16x16x32_bf16(a_h[rt], b_l, acc[rt][ct], 0, 0, 0);
                    acc[rt][ct] = __builtin_amdgcn_mfma_f32_16x16x32_bf16(a_l[rt], b_h, acc[rt][ct], 0, 0, 0);
                }
            }
        }
    }

    // ---- epilogue: C/D layout col = ct*16 + fl, row = base + fg*4 + reg ----
    float bval[8];
    #pragma unroll
    for (int ct = 0; ct < 8; ++ct) bval[ct] = bias ? bias[ct * 16 + fl] : 0.f;
    float asv[8], adv[8];
    if (ATT) {
        #pragma unroll
        for (int ct = 0; ct < 8; ++ct) {
            asv[ct] = att_s[ct * 16 + fl];
            adv[ct] = att_d[ct * 16 + fl];
        }
    }

    #pragma unroll
    for (int rt = 0; rt < 2; ++rt) {
        const int rbase = rowBase + rt * 16 + fg * 4;
        #pragma unroll
        for (int r = 0; r < 4; ++r) {
            const int row = rbase + r;
            const bool ok = row < M;
            float sv = 0.f, dv = 0.f;
            #pragma unroll
            for (int ct = 0; ct < 8; ++ct) {
                float val = acc[rt][ct][r] + bval[ct];
                if (ATT) { sv = fmaf(val, asv[ct], sv); dv = fmaf(val, adv[ct], dv); }
                if (ok) {
                    if (Cf) Cf[(size_t)row * HD + ct * 16 + fl] = val;
                    if (Cb) Cb[(size_t)row * HD + ct * 16 + fl] = f2bf(val);
                }
            }
            if (ATT) {
                #pragma unroll
                for (int o = 1; o < 16; o <<= 1) {    // reduce within 16-lane group
                    sv += __shfl_xor(sv, o);
                    dv += __shfl_xor(dv, o);
                }
                if (fl == 0 && ok) { as_[row] = sv; ad_[row] = dv; }
            }
        }
    }
}

// ---------------------------------------------- fused softmax-aggregation
// One wave per destination node; lane l owns features {2l, 2l+1}.
// Pass 2: lane-parallel weights, shfl broadcast, 8-deep gather pipeline.

__global__ __launch_bounds__(256) void k_agg(const ushort* __restrict__ hpb,
                                             float* __restrict__ h,
                                             const float* __restrict__ as_,
                                             const float* __restrict__ ad_,
                                             const int* __restrict__ row_ptr,
                                             const int* __restrict__ col,
                                             const float* __restrict__ wsrt,
                                             const float* __restrict__ bias,
                                             float* __restrict__ out, int mode) {
    int wave = (blockIdx.x * blockDim.x + threadIdx.x) >> 6;
    int lane = threadIdx.x & 63;
    if (wave >= NN) return;
    const int d = wave;
    const int beg = row_ptr[d], end = row_ptr[d + 1];
    const float adv = ad_[d];

    float mloc = -INFINITY;
    for (int p = beg + lane; p < end; p += 64) {
        float l = as_[col[p]] + adv;
        l = (l >= 0.f) ? l : NEG_SLOPE * l;
        mloc = fmaxf(mloc, l);
    }
    #pragma unroll
    for (int o = 32; o > 0; o >>= 1) mloc = fmaxf(mloc, __shfl_xor(mloc, o));
    const float m = (end > beg) ? mloc : 0.f;

    float ax = 0.f, ay = 0.f, dloc = 0.f;
    for (int base = beg; base < end; base += 64) {
        const int n = min(64, end - base);
        int   s = 0;
        float w = 0.f;
        if (lane < n) {
            s = col[base + lane];
            float l = as_[s] + adv;
            l = (l >= 0.f) ? l : NEG_SLOPE * l;
            w = __expf(l - m) * wsrt[base + lane];
        }
        dloc += w;

        int i = 0;
        for (; i + 7 < n; i += 8) {               // 8 gathers in flight
            float wv[8]; int sv[8]; uint32_t pv[8];
            #pragma unroll
            for (int j = 0; j < 8; ++j) {
                wv[j] = __shfl(w, i + j);
                sv[j] = __shfl(s, i + j);
            }
            #pragma unroll
            for (int j = 0; j < 8; ++j)
                pv[j] = *reinterpret_cast<const uint32_t*>(hpb + (size_t)sv[j] * HD + lane * 2);
            #pragma unroll
            for (int j = 0; j < 8; ++j) {
                ax = fmaf(wv[j], bf2f((ushort)pv[j]), ax);
                ay = fmaf(wv[j], bf2f((ushort)(pv[j] >> 16)), ay);
            }
        }
        for (; i < n; ++i) {
            float wi = __shfl(w, i);
            int   si = __shfl(s, i);
            uint32_t pv = *reinterpret_cast<const uint32_t*>(hpb + (size_t)si * HD + lane * 2);
            ax = fmaf(wi, bf2f((ushort)pv), ax); ay = fmaf(wi, bf2f((ushort)(pv >> 16)), ay);
        }
    }
    #pragma unroll
    for (int o = 32; o > 0; o >>= 1) dloc += __shfl_xor(dloc, o);

    const float inv = 1.f / (dloc + 1e-16f);
    const float r0 = ax * inv + bias[lane * 2];
    const float r1 = ay * inv + bias[lane * 2 + 1];

    const size_t off = (size_t)d * HD + lane * 2;
    if (mode == 2) {
        float2 o = *reinterpret_cast<float2*>(out + off);
        o.x = fmaxf(o.x, r0); o.y = fmaxf(o.y, r1);
        *reinterpret_cast<float2*>(out + off) = o;
    } else {
        float2 hv = *reinterpret_cast<float2*>(h + off);
        hv.x += r0; hv.y += r1;
        *reinterpret_cast<float2*>(h + off) = hv;
        if (mode == 0) {
            *reinterpret_cast<float2*>(out + off) = hv;
        } else {
            float2 o = *reinterpret_cast<float2*>(out + off);
            o.x = fmaxf(o.x, hv.x); o.y = fmaxf(o.y, hv.y);
            *reinterpret_cast<float2*>(out + off) = o;
        }
    }
}

// ---------------------------------------------------------------- launch

extern "C" void kernel_launch(void* const* d_in, const int* in_sizes, int n_in,
                              void* d_out, int out_size, void* d_ws, size_t ws_size,
                              hipStream_t stream) {
    const float* x        = (const float*)d_in[0];          // [NN][FIN]
    const int*   ei       = (const int*)d_in[1];            // [2][NE]
    const float* ew       = (const float*)d_in[2];          // [NE]
    /* d_in[3] = numNode scalar = NN */
    const float* Wlin     = (const float*)d_in[4];          // [FIN][HD]
    const float* blin     = (const float*)d_in[5];          // [HD]
    const float* Wc       = (const float*)d_in[6];          // [3][HD][HD]
    const float* att_src  = (const float*)d_in[7];          // [3][HD]
    const float* att_dst  = (const float*)d_in[8];          // [3][HD]
    const float* bias_c   = (const float*)d_in[9];          // [3][HD]
    float* out = (float*)d_out;                              // [NN][HD]

    const int* src = ei;
    const int* dst = ei + NE;

    // workspace layout (16B-aligned blocks, ~52 MB)
    char* w = (char*)d_ws;
    float*  h       = (float*)w;   w += (size_t)NN * HD * 4;
    ushort* hpb     = (ushort*)w;  w += (size_t)NN * HD * 2;
    float*  as_     = (float*)w;   w += (size_t)NN * 4;
    float*  ad_     = (float*)w;   w += (size_t)NN * 4;
    int*    row_ptr = (int*)w;     w += (size_t)(NN + 4) * 4;
    int*    col     = (int*)w;     w += (size_t)NE * 4;
    float*  wsrt    = (float*)w;   w += (size_t)NE * 4;
    uint2*  epk     = (uint2*)w;   w += (size_t)NE * 8;
    int*    bhist   = (int*)w;     w += (size_t)NCH * NBK * 4;
    int*    bbeg    = (int*)w;     w += (size_t)(NBK + 4) * 4;
    ushort* WTh     = (ushort*)w;  w += (size_t)(HD * FIN + 3 * HD * HD) * 2;
    ushort* WTl     = (ushort*)w;  w += (size_t)(HD * FIN + 3 * HD * HD) * 2;
    ushort* WlinTh = WTh,            *WlinTl = WTl;
    ushort* WcTh   = WTh + HD * FIN, *WcTl   = WTl + HD * FIN;

    const int TB = 256;
    const int nblk_w = (NN * 64 + TB - 1) / TB;      // one wave per node
    const int nblk_g = (NN + 127) / 128;             // 391 (128 rows per block)

    // ---- weight transpose + split (tiny) ----
    k_split<<<(HD * FIN + TB - 1) / TB, TB, 0, stream>>>(Wlin, WlinTh, WlinTl, FIN);
    for (int l = 0; l < 3; ++l)
        k_split<<<(HD * HD + TB - 1) / TB, TB, 0, stream>>>(
            Wc + (size_t)l * HD * HD, WcTh + (size_t)l * HD * HD,
            WcTl + (size_t)l * HD * HD, HD);

    // ---- CSR build (atomic-reservation-free binning) ----
    k_bhist<<<NCH, 1024, 0, stream>>>(dst, bhist);
    k_bscan<<<1, 256, 0, stream>>>(bhist, bbeg, row_ptr);
    k_binscatter<<<NCH, 1024, 0, stream>>>(src, dst, ew, bhist, epk);
    k_build<<<NBK, 256, 0, stream>>>(epk, bbeg, row_ptr, col, wsrt);

    // ---- input projection: h = x @ Wlin + blin (fp32 out) ----
    k_gemm_mfma<FIN, false><<<nblk_g, TB, 0, stream>>>(
        x, WlinTh, WlinTl, blin, h, nullptr, nullptr, nullptr, nullptr, nullptr, NN);

    // ---- 3 GAT layers ----
    for (int layer = 0; layer < 3; ++layer) {
        k_gemm_mfma<HD, true><<<nblk_g, TB, 0, stream>>>(
            h, WcTh + (size_t)layer * HD * HD, WcTl + (size_t)layer * HD * HD,
            nullptr, nullptr, hpb,
            att_src + layer * HD, att_dst + layer * HD, as_, ad_, NN);
        int mode = (layer == 0) ? 0 : (layer == 2 ? 2 : 1);
        k_agg<<<nblk_w, TB, 0, stream>>>(hpb, h, as_, ad_, row_ptr, col, wsrt,
                                         bias_c + layer * HD, out, mode);
    }
}

// Round 7
// 255.162 us; speedup vs baseline: 1.4694x; 1.0224x over previous
//
#include <hip/hip_runtime.h>
#include <cstdint>
#include <cstddef>

// Problem constants (from reference)
#define NN 50000
#define NE 800000
#define FIN 256
#define HD 128
#define NEG_SLOPE 0.2f

// CSR-build binning parameters
#define NBK 196          // buckets of 256 nodes: ceil(50000/256)
#define NCH 98           // edge chunks
#define CHUNK 8192       // edges per chunk (98*8192 >= 800000)

typedef short s16x8 __attribute__((ext_vector_type(8)));   // 8 bf16 (4 VGPRs)
typedef float f32x4 __attribute__((ext_vector_type(4)));   // MFMA accumulator

__device__ inline ushort f2bf(float f) {                   // fp32 -> bf16 RTN-even
    uint32_t u = __float_as_uint(f);
    u += 0x7FFFu + ((u >> 16) & 1u);
    return (ushort)(u >> 16);
}
__device__ inline float bf2f(ushort h) {
    return __uint_as_float(((uint32_t)h) << 16);
}

// ------------------------------------------------------------- CSR build
// bucket = dst >> 8. No global atomics anywhere.

__global__ __launch_bounds__(1024) void k_bhist(const int* __restrict__ dst,
                                                int* __restrict__ bhist) {
    __shared__ int hist[NBK];
    const int tid = threadIdx.x, blk = blockIdx.x;
    if (tid < NBK) hist[tid] = 0;
    __syncthreads();
    const int e0 = blk * CHUNK;
    #pragma unroll
    for (int u = 0; u < CHUNK / 1024; ++u) {
        int e = e0 + u * 1024 + tid;
        if (e < NE) atomicAdd(&hist[dst[e] >> 8], 1);
    }
    __syncthreads();
    if (tid < NBK) bhist[blk * NBK + tid] = hist[tid];
}

__global__ __launch_bounds__(256) void k_bscan(int* __restrict__ bhist,
                                               int* __restrict__ bbeg,
                                               int* __restrict__ row_ptr) {
    __shared__ int wsum[4];
    const int tid = threadIdx.x;
    int tot = 0;
    if (tid < NBK) {
        for (int c = 0; c < NCH; ++c) {           // coalesced across tid
            int t = bhist[c * NBK + tid];
            bhist[c * NBK + tid] = tot;           // per-bucket chunk prefix
            tot += t;
        }
    }
    const int lane = tid & 63, wid = tid >> 6;
    int x = tot;
    #pragma unroll
    for (int o = 1; o < 64; o <<= 1) {
        int t = __shfl_up(x, o);
        if (lane >= o) x += t;
    }
    if (lane == 63) wsum[wid] = x;
    __syncthreads();
    int wo = 0;
    for (int k = 0; k < wid; ++k) wo += wsum[k];
    const int excl = x - tot + wo;                // bucket start offset
    if (tid < NBK) bbeg[tid] = excl;
    if (tid == 0) { bbeg[NBK] = NE; row_ptr[NN] = NE; }
    __syncthreads();
    if (tid < NBK)
        for (int c = 0; c < NCH; ++c) bhist[c * NBK + tid] += excl;
}

__global__ __launch_bounds__(1024) void k_binscatter(const int* __restrict__ src,
                                                     const int* __restrict__ dst,
                                                     const float* __restrict__ ew,
                                                     const int* __restrict__ bhist,
                                                     uint2* __restrict__ epk) {
    __shared__ int base[NBK];
    __shared__ int lcur[NBK];
    const int tid = threadIdx.x, blk = blockIdx.x;
    if (tid < NBK) { base[tid] = bhist[blk * NBK + tid]; lcur[tid] = 0; }
    __syncthreads();
    const int e0 = blk * CHUNK;
    #pragma unroll
    for (int u = 0; u < CHUNK / 1024; ++u) {
        int e = e0 + u * 1024 + tid;
        if (e < NE) {
            int d = dst[e];
            int s = src[e];
            float w = ew[e];
            int b = d >> 8;
            int pos = base[b] + atomicAdd(&lcur[b], 1);   // LDS atomic only
            epk[pos] = make_uint2((uint32_t)s | ((uint32_t)(d & 255) << 16),
                                  __float_as_uint(w));
        }
    }
}

__global__ __launch_bounds__(256) void k_build(const uint2* __restrict__ epk,
                                               const int* __restrict__ bbeg,
                                               int* __restrict__ row_ptr,
                                               int* __restrict__ col,
                                               float* __restrict__ wsrt) {
    __shared__ int cnt[256];
    __shared__ int cur[256];
    __shared__ int wsum[4];
    const int tid = threadIdx.x, b = blockIdx.x;
    const int n0 = b << 8;
    const int ebeg = bbeg[b], eend = bbeg[b + 1];
    cnt[tid] = 0;
    __syncthreads();
    for (int e = ebeg + tid; e < eend; e += 256)
        atomicAdd(&cnt[(epk[e].x >> 16) & 255], 1);
    __syncthreads();
    const int v = cnt[tid];
    const int lane = tid & 63, wid = tid >> 6;
    int x = v;
    #pragma unroll
    for (int o = 1; o < 64; o <<= 1) {
        int t = __shfl_up(x, o);
        if (lane >= o) x += t;
    }
    if (lane == 63) wsum[wid] = x;
    __syncthreads();
    int wo = 0;
    for (int k = 0; k < wid; ++k) wo += wsum[k];
    const int excl = ebeg + x - v + wo;           // node segment start
    if (n0 + tid < NN) row_ptr[n0 + tid] = excl;
    cur[tid] = excl;
    __syncthreads();
    for (int e = ebeg + tid; e < eend; e += 256) {
        uint2 p = epk[e];
        int dl = (p.x >> 16) & 255;
        int pos = atomicAdd(&cur[dl], 1);
        col[pos]  = (int)(p.x & 0xFFFFu);
        wsrt[pos] = __uint_as_float(p.y);
    }
}

// -------------------------------------------- weight transpose + bf16 split
// W [K][HD] fp32 row-major -> Th/Tl [HD][K] bf16 (hi + residual-lo)

__global__ void k_split(const float* __restrict__ W, ushort* __restrict__ Th,
                        ushort* __restrict__ Tl, int K) {
    int idx = blockIdx.x * blockDim.x + threadIdx.x;   // = n*K + k
    if (idx >= K * HD) return;
    int n = idx / K, k = idx - n * K;
    float f = W[(size_t)k * HD + n];
    ushort hi = f2bf(f);
    Th[idx] = hi;
    Tl[idx] = f2bf(f - bf2f(hi));
}

// ----------------------------------------------------- MFMA split-bf16 GEMM
// C[M][128] = A[M][K] @ B[K][128] (+bias), 16x16x32 bf16 MFMA,
// D = Ahi*Bhi + Ahi*Blo + Alo*Bhi  (~fp32 accuracy).
// B^T hi/lo for a whole BK=128 K-tile staged ONCE into LDS (64 KB,
// XOR-swizzled 16B chunks), then a barrier-free main loop.

template <int K, bool ATT>
__global__ __launch_bounds__(256) void k_gemm_mfma(
    const float*  __restrict__ A,
    const ushort* __restrict__ Bh,     // [HD][K]
    const ushort* __restrict__ Bl,     // [HD][K]
    const float*  __restrict__ bias,   // null if none
    float*        __restrict__ Cf,     // fp32 out (null if unused)
    ushort*       __restrict__ Cb,     // bf16 out (null if unused)
    const float*  __restrict__ att_s, const float* __restrict__ att_d,
    float* __restrict__ as_, float* __restrict__ ad_,
    int M)
{
    constexpr int BK = 128;                       // K-elems per LDS tile
    constexpr int NT = K / BK;                    // 1 or 2 tiles
    __shared__ ushort Bs[32768];                  // 64 KB: hi [0..16383], lo +16384

    const int tid  = threadIdx.x;
    const int lane = tid & 63;
    const int wid  = tid >> 6;
    const int fl   = lane & 15;                   // A row / B col within frag
    const int fg   = lane >> 4;                   // k-group (8 elems)
    const int rowBase = blockIdx.x * 128 + wid * 32;

    f32x4 acc[2][8] = {};

    for (int t = 0; t < NT; ++t) {
        if (t) __syncthreads();                   // all waves done with tile t-1
        #pragma unroll
        for (int u = 0; u < 8; ++u) {
            const int id  = u * 256 + tid;
            const int bcol = id >> 4, c = id & 15;
            const size_t g = (size_t)bcol * K + t * BK + c * 8;
            const int lidx = bcol * 128 + ((c ^ (bcol & 15)) << 3);
            *reinterpret_cast<uint4*>(&Bs[lidx]) =
                *reinterpret_cast<const uint4*>(Bh + g);
            *reinterpret_cast<uint4*>(&Bs[16384 + lidx]) =
                *reinterpret_cast<const uint4*>(Bl + g);
        }
        __syncthreads();

        #pragma unroll
        for (int kt = 0; kt < BK / 32; ++kt) {
            s16x8 a_h[2], a_l[2];
            #pragma unroll
            for (int rt = 0; rt < 2; ++rt) {
                int r = rowBase + rt * 16 + fl;
                if (r >= M) r = M - 1;            // harmless clamp (stores guarded)
                const float* ap = A + (size_t)r * K + t * BK + kt * 32 + fg * 8;
                float4 t0 = *reinterpret_cast<const float4*>(ap);
                float4 t1 = *reinterpret_cast<const float4*>(ap + 4);
                float v[8] = {t0.x, t0.y, t0.z, t0.w, t1.x, t1.y, t1.z, t1.w};
                #pragma unroll
                for (int u = 0; u < 8; ++u) {
                    ushort h0 = f2bf(v[u]);
                    a_h[rt][u] = (short)h0;
                    a_l[rt][u] = (short)f2bf(v[u] - bf2f(h0));
                }
            }
            #pragma unroll
            for (int ct = 0; ct < 8; ++ct) {
                const int lidx = (ct * 16 + fl) * 128 + (((kt * 4 + fg) ^ fl) << 3);
                s16x8 b_h = *reinterpret_cast<const s16x8*>(&Bs[lidx]);
                s16x8 b_l = *reinterpret_cast<const s16x8*>(&Bs[16384 + lidx]);
                #pragma unroll
                for (int rt = 0; rt < 2; ++rt) {
                    acc[rt][ct] = __builtin_amdgcn_mfma_f32_16x16x32_bf16(a_h[rt], b_h, acc[rt][ct], 0, 0, 0);
                    acc[rt][ct] = __builtin_amdgcn_mfma_f32_16x16x32_bf16(a_h[rt], b_l, acc[rt][ct], 0, 0, 0);
                    acc[rt][ct] = __builtin_amdgcn_mfma_f32_16x16x32_bf16(a_l[rt], b_h, acc[rt][ct], 0, 0, 0);
                }
            }
        }
    }

    // ---- epilogue: C/D layout col = ct*16 + fl, row = base + fg*4 + reg ----
    float bval[8];
    #pragma unroll
    for (int ct = 0; ct < 8; ++ct) bval[ct] = bias ? bias[ct * 16 + fl] : 0.f;
    float asv[8], adv[8];
    if (ATT) {
        #pragma unroll
        for (int ct = 0; ct < 8; ++ct) {
            asv[ct] = att_s[ct * 16 + fl];
            adv[ct] = att_d[ct * 16 + fl];
        }
    }

    #pragma unroll
    for (int rt = 0; rt < 2; ++rt) {
        const int rbase = rowBase + rt * 16 + fg * 4;
        #pragma unroll
        for (int r = 0; r < 4; ++r) {
            const int row = rbase + r;
            const bool ok = row < M;
            float sv = 0.f, dv = 0.f;
            #pragma unroll
            for (int ct = 0; ct < 8; ++ct) {
                float val = acc[rt][ct][r] + bval[ct];
                if (ATT) { sv = fmaf(val, asv[ct], sv); dv = fmaf(val, adv[ct], dv); }
                if (ok) {
                    if (Cf) Cf[(size_t)row * HD + ct * 16 + fl] = val;
                    if (Cb) Cb[(size_t)row * HD + ct * 16 + fl] = f2bf(val);
                }
            }
            if (ATT) {
                #pragma unroll
                for (int o = 1; o < 16; o <<= 1) {    // reduce within 16-lane group
                    sv += __shfl_xor(sv, o);
                    dv += __shfl_xor(dv, o);
                }
                if (fl == 0 && ok) { as_[row] = sv; ad_[row] = dv; }
            }
        }
    }
}

// ---------------------------------------------- fused softmax-aggregation
// One wave per destination node. Pass 2: lane owns 4 features (uint2=8B),
// 32 lanes cover a row; the two wave halves process edges i and i+1 of the
// SAME node simultaneously (one load instruction = 2 rows = 512 B). 4 loads
// (8 edges) in flight. Final __shfl_xor(.,32) folds the halves; lanes 0-31
// store float4.
// mode: 0 = h += agg (no out); 1 = out = max(h_old, h_old+agg), h += agg;
// 2 = out = max(out, agg + b).

__global__ __launch_bounds__(256) void k_agg(const ushort* __restrict__ hpb,
                                             float* __restrict__ h,
                                             const float* __restrict__ as_,
                                             const float* __restrict__ ad_,
                                             const int* __restrict__ row_ptr,
                                             const int* __restrict__ col,
                                             const float* __restrict__ wsrt,
                                             const float* __restrict__ bias,
                                             float* __restrict__ out, int mode) {
    int wave = (blockIdx.x * blockDim.x + threadIdx.x) >> 6;
    int lane = threadIdx.x & 63;
    if (wave >= NN) return;
    const int d = wave;
    const int beg = row_ptr[d], end = row_ptr[d + 1];
    const float adv = ad_[d];
    const int half = lane >> 5;        // which of the 2 in-flight edges
    const int hl   = lane & 31;        // feature group: owns [hl*4, hl*4+4)

    // pass 1: lane-parallel segment max of leaky_relu(as[src] + ad[dst])
    float mloc = -INFINITY;
    for (int p = beg + lane; p < end; p += 64) {
        float l = as_[col[p]] + adv;
        l = (l >= 0.f) ? l : NEG_SLOPE * l;
        mloc = fmaxf(mloc, l);
    }
    #pragma unroll
    for (int o = 32; o > 0; o >>= 1) mloc = fmaxf(mloc, __shfl_xor(mloc, o));
    const float m = (end > beg) ? mloc : 0.f;

    // pass 2: chunked lane-parallel weights + paired broadcast accumulation
    float a0 = 0.f, a1 = 0.f, a2 = 0.f, a3 = 0.f, dloc = 0.f;
    for (int base = beg; base < end; base += 64) {
        const int n = min(64, end - base);
        int   s = 0;
        float w = 0.f;
        if (lane < n) {
            s = col[base + lane];
            float l = as_[s] + adv;
            l = (l >= 0.f) ? l : NEG_SLOPE * l;
            w = __expf(l - m) * wsrt[base + lane];
        }
        dloc += w;

        int i = 0;
        for (; i + 7 < n; i += 8) {            // 8 edges = 4 paired loads in flight
            float wv[4]; int sv[4]; uint2 pv[4];
            #pragma unroll
            for (int j = 0; j < 4; ++j) {
                const int idx = i + 2 * j + half;
                wv[j] = __shfl(w, idx);
                sv[j] = __shfl(s, idx);
            }
            #pragma unroll
            for (int j = 0; j < 4; ++j)
                pv[j] = *reinterpret_cast<const uint2*>(hpb + (size_t)sv[j] * HD + hl * 4);
            #pragma unroll
            for (int j = 0; j < 4; ++j) {
                a0 = fmaf(wv[j], bf2f((ushort)pv[j].x),         a0);
                a1 = fmaf(wv[j], bf2f((ushort)(pv[j].x >> 16)), a1);
                a2 = fmaf(wv[j], bf2f((ushort)pv[j].y),         a2);
                a3 = fmaf(wv[j], bf2f((ushort)(pv[j].y >> 16)), a3);
            }
        }
        for (; i < n; i += 2) {                // tail (handles odd counts)
            const int e = i + half;
            const int idx = (e < n) ? e : i;
            float wj = __shfl(w, idx);
            int   sj = __shfl(s, idx);
            if (e >= n) wj = 0.f;
            uint2 pv = *reinterpret_cast<const uint2*>(hpb + (size_t)sj * HD + hl * 4);
            a0 = fmaf(wj, bf2f((ushort)pv.x),         a0);
            a1 = fmaf(wj, bf2f((ushort)(pv.x >> 16)), a1);
            a2 = fmaf(wj, bf2f((ushort)pv.y),         a2);
            a3 = fmaf(wj, bf2f((ushort)(pv.y >> 16)), a3);
        }
    }
    #pragma unroll
    for (int o = 32; o > 0; o >>= 1) dloc += __shfl_xor(dloc, o);
    a0 += __shfl_xor(a0, 32);
    a1 += __shfl_xor(a1, 32);
    a2 += __shfl_xor(a2, 32);
    a3 += __shfl_xor(a3, 32);

    if (half != 0) return;                     // lanes 0-31 do the stores
    const float inv = 1.f / (dloc + 1e-16f);
    const int f0 = hl * 4;
    float4 r;
    r.x = a0 * inv + bias[f0 + 0];
    r.y = a1 * inv + bias[f0 + 1];
    r.z = a2 * inv + bias[f0 + 2];
    r.w = a3 * inv + bias[f0 + 3];

    float4* outp = reinterpret_cast<float4*>(out + (size_t)d * HD + f0);
    float4* hp4  = reinterpret_cast<float4*>(h   + (size_t)d * HD + f0);
    if (mode == 2) {
        float4 o = *outp;
        o.x = fmaxf(o.x, r.x); o.y = fmaxf(o.y, r.y);
        o.z = fmaxf(o.z, r.z); o.w = fmaxf(o.w, r.w);
        *outp = o;
    } else {
        float4 hv = *hp4;
        float4 hn;
        hn.x = hv.x + r.x; hn.y = hv.y + r.y;
        hn.z = hv.z + r.z; hn.w = hv.w + r.w;
        *hp4 = hn;
        if (mode == 1) {                        // out = max(h1, h2), no out read
            float4 mx;
            mx.x = fmaxf(hv.x, hn.x); mx.y = fmaxf(hv.y, hn.y);
            mx.z = fmaxf(hv.z, hn.z); mx.w = fmaxf(hv.w, hn.w);
            *outp = mx;
        }
    }
}

// ---------------------------------------------------------------- launch

extern "C" void kernel_launch(void* const* d_in, const int* in_sizes, int n_in,
                              void* d_out, int out_size, void* d_ws, size_t ws_size,
                              hipStream_t stream) {
    const float* x        = (const float*)d_in[0];          // [NN][FIN]
    const int*   ei       = (const int*)d_in[1];            // [2][NE]
    const float* ew       = (const float*)d_in[2];          // [NE]
    /* d_in[3] = numNode scalar = NN */
    const float* Wlin     = (const float*)d_in[4];          // [FIN][HD]
    const float* blin     = (const float*)d_in[5];          // [HD]
    const float* Wc       = (const float*)d_in[6];          // [3][HD][HD]
    const float* att_src  = (const float*)d_in[7];          // [3][HD]
    const float* att_dst  = (const float*)d_in[8];          // [3][HD]
    const float* bias_c   = (const float*)d_in[9];          // [3][HD]
    float* out = (float*)d_out;                              // [NN][HD]

    const int* src = ei;
    const int* dst = ei + NE;

    // workspace layout (16B-aligned blocks, ~52 MB)
    char* w = (char*)d_ws;
    float*  h       = (float*)w;   w += (size_t)NN * HD * 4;
    ushort* hpb     = (ushort*)w;  w += (size_t)NN * HD * 2;
    float*  as_     = (float*)w;   w += (size_t)NN * 4;
    float*  ad_     = (float*)w;   w += (size_t)NN * 4;
    int*    row_ptr = (int*)w;     w += (size_t)(NN + 4) * 4;
    int*    col     = (int*)w;     w += (size_t)NE * 4;
    float*  wsrt    = (float*)w;   w += (size_t)NE * 4;
    uint2*  epk     = (uint2*)w;   w += (size_t)NE * 8;
    int*    bhist   = (int*)w;     w += (size_t)NCH * NBK * 4;
    int*    bbeg    = (int*)w;     w += (size_t)(NBK + 4) * 4;
    ushort* WTh     = (ushort*)w;  w += (size_t)(HD * FIN + 3 * HD * HD) * 2;
    ushort* WTl     = (ushort*)w;  w += (size_t)(HD * FIN + 3 * HD * HD) * 2;
    ushort* WlinTh = WTh,            *WlinTl = WTl;
    ushort* WcTh   = WTh + HD * FIN, *WcTl   = WTl + HD * FIN;

    const int TB = 256;
    const int nblk_w = (NN * 64 + TB - 1) / TB;      // one wave per node
    const int nblk_g = (NN + 127) / 128;             // 391 (128 rows per block)

    // ---- weight transpose + split (tiny) ----
    k_split<<<(HD * FIN + TB - 1) / TB, TB, 0, stream>>>(Wlin, WlinTh, WlinTl, FIN);
    for (int l = 0; l < 3; ++l)
        k_split<<<(HD * HD + TB - 1) / TB, TB, 0, stream>>>(
            Wc + (size_t)l * HD * HD, WcTh + (size_t)l * HD * HD,
            WcTl + (size_t)l * HD * HD, HD);

    // ---- CSR build (atomic-reservation-free binning) ----
    k_bhist<<<NCH, 1024, 0, stream>>>(dst, bhist);
    k_bscan<<<1, 256, 0, stream>>>(bhist, bbeg, row_ptr);
    k_binscatter<<<NCH, 1024, 0, stream>>>(src, dst, ew, bhist, epk);
    k_build<<<NBK, 256, 0, stream>>>(epk, bbeg, row_ptr, col, wsrt);

    // ---- input projection: h = x @ Wlin + blin (fp32 out) ----
    k_gemm_mfma<FIN, false><<<nblk_g, TB, 0, stream>>>(
        x, WlinTh, WlinTl, blin, h, nullptr, nullptr, nullptr, nullptr, nullptr, NN);

    // ---- 3 GAT layers ----
    for (int layer = 0; layer < 3; ++layer) {
        k_gemm_mfma<HD, true><<<nblk_g, TB, 0, stream>>>(
            h, WcTh + (size_t)layer * HD * HD, WcTl + (size_t)layer * HD * HD,
            nullptr, nullptr, hpb,
            att_src + layer * HD, att_dst + layer * HD, as_, ad_, NN);
        int mode = (layer == 0) ? 0 : (layer == 2 ? 2 : 1);
        k_agg<<<nblk_w, TB, 0, stream>>>(hpb, h, as_, ad_, row_ptr, col, wsrt,
                                         bias_c + layer * HD, out, mode);
    }
}

// Round 8
// 244.280 us; speedup vs baseline: 1.5348x; 1.0445x over previous
//
#include <hip/hip_runtime.h>
#include <cstdint>
#include <cstddef>

// Problem constants (from reference)
#define NN 50000
#define NE 800000
#define FIN 256
#define HD 128
#define NEG_SLOPE 0.2f

// CSR-build binning parameters
#define NBK 196          // buckets of 256 nodes: ceil(50000/256)
#define NCH 98           // edge chunks
#define CHUNK 8192       // edges per chunk (98*8192 >= 800000)

typedef short s16x8 __attribute__((ext_vector_type(8)));   // 8 bf16 (4 VGPRs)
typedef float f32x4 __attribute__((ext_vector_type(4)));   // MFMA accumulator

__device__ inline ushort f2bf(float f) {                   // fp32 -> bf16 RTN-even
    uint32_t u = __float_as_uint(f);
    u += 0x7FFFu + ((u >> 16) & 1u);
    return (ushort)(u >> 16);
}
__device__ inline float bf2f(ushort h) {
    return __uint_as_float(((uint32_t)h) << 16);
}

// ------------------------------------------------------------- CSR build
// bucket = dst >> 8. No global atomics anywhere.

__global__ __launch_bounds__(1024) void k_bhist(const int* __restrict__ dst,
                                                int* __restrict__ bhist) {
    __shared__ int hist[NBK];
    const int tid = threadIdx.x, blk = blockIdx.x;
    if (tid < NBK) hist[tid] = 0;
    __syncthreads();
    const int e0 = blk * CHUNK;
    #pragma unroll
    for (int u = 0; u < CHUNK / 1024; ++u) {
        int e = e0 + u * 1024 + tid;
        if (e < NE) atomicAdd(&hist[dst[e] >> 8], 1);
    }
    __syncthreads();
    if (tid < NBK) bhist[blk * NBK + tid] = hist[tid];
}

__global__ __launch_bounds__(256) void k_bscan(int* __restrict__ bhist,
                                               int* __restrict__ bbeg,
                                               int* __restrict__ row_ptr) {
    __shared__ int wsum[4];
    const int tid = threadIdx.x;
    int tot = 0;
    if (tid < NBK) {
        for (int c = 0; c < NCH; ++c) {           // coalesced across tid
            int t = bhist[c * NBK + tid];
            bhist[c * NBK + tid] = tot;           // per-bucket chunk prefix
            tot += t;
        }
    }
    const int lane = tid & 63, wid = tid >> 6;
    int x = tot;
    #pragma unroll
    for (int o = 1; o < 64; o <<= 1) {
        int t = __shfl_up(x, o);
        if (lane >= o) x += t;
    }
    if (lane == 63) wsum[wid] = x;
    __syncthreads();
    int wo = 0;
    for (int k = 0; k < wid; ++k) wo += wsum[k];
    const int excl = x - tot + wo;                // bucket start offset
    if (tid < NBK) bbeg[tid] = excl;
    if (tid == 0) { bbeg[NBK] = NE; row_ptr[NN] = NE; }
    __syncthreads();
    if (tid < NBK)
        for (int c = 0; c < NCH; ++c) bhist[c * NBK + tid] += excl;
}

__global__ __launch_bounds__(1024) void k_binscatter(const int* __restrict__ src,
                                                     const int* __restrict__ dst,
                                                     const float* __restrict__ ew,
                                                     const int* __restrict__ bhist,
                                                     uint2* __restrict__ epk) {
    __shared__ int base[NBK];
    __shared__ int lcur[NBK];
    const int tid = threadIdx.x, blk = blockIdx.x;
    if (tid < NBK) { base[tid] = bhist[blk * NBK + tid]; lcur[tid] = 0; }
    __syncthreads();
    const int e0 = blk * CHUNK;
    #pragma unroll
    for (int u = 0; u < CHUNK / 1024; ++u) {
        int e = e0 + u * 1024 + tid;
        if (e < NE) {
            int d = dst[e];
            int s = src[e];
            float w = ew[e];
            int b = d >> 8;
            int pos = base[b] + atomicAdd(&lcur[b], 1);   // LDS atomic only
            epk[pos] = make_uint2((uint32_t)s | ((uint32_t)(d & 255) << 16),
                                  __float_as_uint(w));
        }
    }
}

__global__ __launch_bounds__(256) void k_build(const uint2* __restrict__ epk,
                                               const int* __restrict__ bbeg,
                                               int* __restrict__ row_ptr,
                                               int* __restrict__ col,
                                               float* __restrict__ wsrt) {
    __shared__ int cnt[256];
    __shared__ int cur[256];
    __shared__ int wsum[4];
    const int tid = threadIdx.x, b = blockIdx.x;
    const int n0 = b << 8;
    const int ebeg = bbeg[b], eend = bbeg[b + 1];
    cnt[tid] = 0;
    __syncthreads();
    for (int e = ebeg + tid; e < eend; e += 256)
        atomicAdd(&cnt[(epk[e].x >> 16) & 255], 1);
    __syncthreads();
    const int v = cnt[tid];
    const int lane = tid & 63, wid = tid >> 6;
    int x = v;
    #pragma unroll
    for (int o = 1; o < 64; o <<= 1) {
        int t = __shfl_up(x, o);
        if (lane >= o) x += t;
    }
    if (lane == 63) wsum[wid] = x;
    __syncthreads();
    int wo = 0;
    for (int k = 0; k < wid; ++k) wo += wsum[k];
    const int excl = ebeg + x - v + wo;           // node segment start
    if (n0 + tid < NN) row_ptr[n0 + tid] = excl;
    cur[tid] = excl;
    __syncthreads();
    for (int e = ebeg + tid; e < eend; e += 256) {
        uint2 p = epk[e];
        int dl = (p.x >> 16) & 255;
        int pos = atomicAdd(&cur[dl], 1);
        col[pos]  = (int)(p.x & 0xFFFFu);
        wsrt[pos] = __uint_as_float(p.y);
    }
}

// -------------------------------------------- weight transpose + bf16 split
// W [K][HD] fp32 row-major -> Th/Tl [HD][K] bf16 (hi + residual-lo)

__global__ void k_split(const float* __restrict__ W, ushort* __restrict__ Th,
                        ushort* __restrict__ Tl, int K) {
    int idx = blockIdx.x * blockDim.x + threadIdx.x;   // = n*K + k
    if (idx >= K * HD) return;
    int n = idx / K, k = idx - n * K;
    float f = W[(size_t)k * HD + n];
    ushort hi = f2bf(f);
    Th[idx] = hi;
    Tl[idx] = f2bf(f - bf2f(hi));
}

// ----------------------------------------------------- MFMA split-bf16 GEMM
// C[M][128] = A[M][K] @ B[K][128] (+bias), 16x16x32 bf16 MFMA,
// D = Ahi*Bhi + Ahi*Blo + Alo*Bhi  (~fp32 accuracy).
// B^T hi/lo for a whole BK=128 K-tile staged ONCE into LDS (64 KB,
// XOR-swizzled 16B chunks), then a barrier-free main loop.

template <int K, bool ATT>
__global__ __launch_bounds__(256) void k_gemm_mfma(
    const float*  __restrict__ A,
    const ushort* __restrict__ Bh,     // [HD][K]
    const ushort* __restrict__ Bl,     // [HD][K]
    const float*  __restrict__ bias,   // null if none
    float*        __restrict__ Cf,     // fp32 out (null if unused)
    ushort*       __restrict__ Cb,     // bf16 out (null if unused)
    const float*  __restrict__ att_s, const float* __restrict__ att_d,
    float* __restrict__ as_, float* __restrict__ ad_,
    int M)
{
    constexpr int BK = 128;                       // K-elems per LDS tile
    constexpr int NT = K / BK;                    // 1 or 2 tiles
    __shared__ ushort Bs[32768];                  // 64 KB: hi [0..16383], lo +16384

    const int tid  = threadIdx.x;
    const int lane = tid & 63;
    const int wid  = tid >> 6;
    const int fl   = lane & 15;                   // A row / B col within frag
    const int fg   = lane >> 4;                   // k-group (8 elems)
    const int rowBase = blockIdx.x * 128 + wid * 32;

    f32x4 acc[2][8] = {};

    for (int t = 0; t < NT; ++t) {
        if (t) __syncthreads();                   // all waves done with tile t-1
        #pragma unroll
        for (int u = 0; u < 8; ++u) {
            const int id  = u * 256 + tid;
            const int bcol = id >> 4, c = id & 15;
            const size_t g = (size_t)bcol * K + t * BK + c * 8;
            const int lidx = bcol * 128 + ((c ^ (bcol & 15)) << 3);
            *reinterpret_cast<uint4*>(&Bs[lidx]) =
                *reinterpret_cast<const uint4*>(Bh + g);
            *reinterpret_cast<uint4*>(&Bs[16384 + lidx]) =
                *reinterpret_cast<const uint4*>(Bl + g);
        }
        __syncthreads();

        #pragma unroll
        for (int kt = 0; kt < BK / 32; ++kt) {
            s16x8 a_h[2], a_l[2];
            #pragma unroll
            for (int rt = 0; rt < 2; ++rt) {
                int r = rowBase + rt * 16 + fl;
                if (r >= M) r = M - 1;            // harmless clamp (stores guarded)
                const float* ap = A + (size_t)r * K + t * BK + kt * 32 + fg * 8;
                float4 t0 = *reinterpret_cast<const float4*>(ap);
                float4 t1 = *reinterpret_cast<const float4*>(ap + 4);
                float v[8] = {t0.x, t0.y, t0.z, t0.w, t1.x, t1.y, t1.z, t1.w};
                #pragma unroll
                for (int u = 0; u < 8; ++u) {
                    ushort h0 = f2bf(v[u]);
                    a_h[rt][u] = (short)h0;
                    a_l[rt][u] = (short)f2bf(v[u] - bf2f(h0));
                }
            }
            #pragma unroll
            for (int ct = 0; ct < 8; ++ct) {
                const int lidx = (ct * 16 + fl) * 128 + (((kt * 4 + fg) ^ fl) << 3);
                s16x8 b_h = *reinterpret_cast<const s16x8*>(&Bs[lidx]);
                s16x8 b_l = *reinterpret_cast<const s16x8*>(&Bs[16384 + lidx]);
                #pragma unroll
                for (int rt = 0; rt < 2; ++rt) {
                    acc[rt][ct] = __builtin_amdgcn_mfma_f32_16x16x32_bf16(a_h[rt], b_h, acc[rt][ct], 0, 0, 0);
                    acc[rt][ct] = __builtin_amdgcn_mfma_f32_16x16x32_bf16(a_h[rt], b_l, acc[rt][ct], 0, 0, 0);
                    acc[rt][ct] = __builtin_amdgcn_mfma_f32_16x16x32_bf16(a_l[rt], b_h, acc[rt][ct], 0, 0, 0);
                }
            }
        }
    }

    // ---- epilogue: C/D layout col = ct*16 + fl, row = base + fg*4 + reg ----
    float bval[8];
    #pragma unroll
    for (int ct = 0; ct < 8; ++ct) bval[ct] = bias ? bias[ct * 16 + fl] : 0.f;
    float asv[8], adv[8];
    if (ATT) {
        #pragma unroll
        for (int ct = 0; ct < 8; ++ct) {
            asv[ct] = att_s[ct * 16 + fl];
            adv[ct] = att_d[ct * 16 + fl];
        }
    }

    #pragma unroll
    for (int rt = 0; rt < 2; ++rt) {
        const int rbase = rowBase + rt * 16 + fg * 4;
        #pragma unroll
        for (int r = 0; r < 4; ++r) {
            const int row = rbase + r;
            const bool ok = row < M;
            float sv = 0.f, dv = 0.f;
            #pragma unroll
            for (int ct = 0; ct < 8; ++ct) {
                float val = acc[rt][ct][r] + bval[ct];
                if (ATT) { sv = fmaf(val, asv[ct], sv); dv = fmaf(val, adv[ct], dv); }
                if (ok) {
                    if (Cf) Cf[(size_t)row * HD + ct * 16 + fl] = val;
                    if (Cb) Cb[(size_t)row * HD + ct * 16 + fl] = f2bf(val);
                }
            }
            if (ATT) {
                #pragma unroll
                for (int o = 1; o < 16; o <<= 1) {    // reduce within 16-lane group
                    sv += __shfl_xor(sv, o);
                    dv += __shfl_xor(dv, o);
                }
                if (fl == 0 && ok) { as_[row] = sv; ad_[row] = dv; }
            }
        }
    }
}

// ---------------------------------------------- fused softmax-aggregation
// One wave per destination node. NO segment-max pass: softmax is
// shift-invariant (alpha = exp(l)ew / sum exp(l)ew); l clamped at 80 so
// fp32 exp cannot overflow (exp(80)=5.5e34, denom < 3.4e38).
// Lane owns 4 features (uint2=8B), 32 lanes cover a row; the two wave
// halves process edges i and i+half simultaneously. Up to 8 paired loads
// (16 edges = one avg node) in flight. Final __shfl_xor(.,32) folds halves.
// mode: 0 = h += agg (no out); 1 = out = max(h_old, h_old+agg), h += agg;
// 2 = out = max(out, agg + b).

__global__ __launch_bounds__(256) void k_agg(const ushort* __restrict__ hpb,
                                             float* __restrict__ h,
                                             const float* __restrict__ as_,
                                             const float* __restrict__ ad_,
                                             const int* __restrict__ row_ptr,
                                             const int* __restrict__ col,
                                             const float* __restrict__ wsrt,
                                             const float* __restrict__ bias,
                                             float* __restrict__ out, int mode) {
    int wave = (blockIdx.x * blockDim.x + threadIdx.x) >> 6;
    int lane = threadIdx.x & 63;
    if (wave >= NN) return;
    const int d = wave;
    const int beg = row_ptr[d], end = row_ptr[d + 1];
    const float adv = ad_[d];
    const int half = lane >> 5;        // which of the 2 paired edges
    const int hl   = lane & 31;        // feature group: owns [hl*4, hl*4+4)

    float a0 = 0.f, a1 = 0.f, a2 = 0.f, a3 = 0.f, dloc = 0.f;
    for (int base = beg; base < end; base += 64) {
        const int n = min(64, end - base);
        int   s = 0;
        float w = 0.f;
        if (lane < n) {
            s = col[base + lane];
            float l = as_[s] + adv;
            l = (l >= 0.f) ? l : NEG_SLOPE * l;
            l = fminf(l, 80.f);                    // overflow guard (no max pass)
            w = __expf(l) * wsrt[base + lane];
        }
        dloc += w;

        int i = 0;
        for (; i + 15 < n; i += 16) {          // 16 edges = 8 paired loads in flight
            float wv[8]; int sv[8]; uint2 pv[8];
            #pragma unroll
            for (int j = 0; j < 8; ++j) {
                const int idx = i + 2 * j + half;
                wv[j] = __shfl(w, idx);
                sv[j] = __shfl(s, idx);
            }
            #pragma unroll
            for (int j = 0; j < 8; ++j)
                pv[j] = *reinterpret_cast<const uint2*>(hpb + (size_t)sv[j] * HD + hl * 4);
            #pragma unroll
            for (int j = 0; j < 8; ++j) {
                a0 = fmaf(wv[j], bf2f((ushort)pv[j].x),         a0);
                a1 = fmaf(wv[j], bf2f((ushort)(pv[j].x >> 16)), a1);
                a2 = fmaf(wv[j], bf2f((ushort)pv[j].y),         a2);
                a3 = fmaf(wv[j], bf2f((ushort)(pv[j].y >> 16)), a3);
            }
        }
        for (; i + 7 < n; i += 8) {            // 8 edges = 4 paired loads
            float wv[4]; int sv[4]; uint2 pv[4];
            #pragma unroll
            for (int j = 0; j < 4; ++j) {
                const int idx = i + 2 * j + half;
                wv[j] = __shfl(w, idx);
                sv[j] = __shfl(s, idx);
            }
            #pragma unroll
            for (int j = 0; j < 4; ++j)
                pv[j] = *reinterpret_cast<const uint2*>(hpb + (size_t)sv[j] * HD + hl * 4);
            #pragma unroll
            for (int j = 0; j < 4; ++j) {
                a0 = fmaf(wv[j], bf2f((ushort)pv[j].x),         a0);
                a1 = fmaf(wv[j], bf2f((ushort)(pv[j].x >> 16)), a1);
                a2 = fmaf(wv[j], bf2f((ushort)pv[j].y),         a2);
                a3 = fmaf(wv[j], bf2f((ushort)(pv[j].y >> 16)), a3);
            }
        }
        for (; i < n; i += 2) {                // tail (handles odd counts)
            const int e = i + half;
            const int idx = (e < n) ? e : i;
            float wj = __shfl(w, idx);
            int   sj = __shfl(s, idx);
            if (e >= n) wj = 0.f;
            uint2 pv = *reinterpret_cast<const uint2*>(hpb + (size_t)sj * HD + hl * 4);
            a0 = fmaf(wj, bf2f((ushort)pv.x),         a0);
            a1 = fmaf(wj, bf2f((ushort)(pv.x >> 16)), a1);
            a2 = fmaf(wj, bf2f((ushort)pv.y),         a2);
            a3 = fmaf(wj, bf2f((ushort)(pv.y >> 16)), a3);
        }
    }
    #pragma unroll
    for (int o = 32; o > 0; o >>= 1) dloc += __shfl_xor(dloc, o);
    a0 += __shfl_xor(a0, 32);
    a1 += __shfl_xor(a1, 32);
    a2 += __shfl_xor(a2, 32);
    a3 += __shfl_xor(a3, 32);

    if (half != 0) return;                     // lanes 0-31 do the stores
    const float inv = 1.f / (dloc + 1e-16f);
    const int f0 = hl * 4;
    float4 r;
    r.x = a0 * inv + bias[f0 + 0];
    r.y = a1 * inv + bias[f0 + 1];
    r.z = a2 * inv + bias[f0 + 2];
    r.w = a3 * inv + bias[f0 + 3];

    float4* outp = reinterpret_cast<float4*>(out + (size_t)d * HD + f0);
    float4* hp4  = reinterpret_cast<float4*>(h   + (size_t)d * HD + f0);
    if (mode == 2) {
        float4 o = *outp;
        o.x = fmaxf(o.x, r.x); o.y = fmaxf(o.y, r.y);
        o.z = fmaxf(o.z, r.z); o.w = fmaxf(o.w, r.w);
        *outp = o;
    } else {
        float4 hv = *hp4;
        float4 hn;
        hn.x = hv.x + r.x; hn.y = hv.y + r.y;
        hn.z = hv.z + r.z; hn.w = hv.w + r.w;
        *hp4 = hn;
        if (mode == 1) {                        // out = max(h1, h2), no out read
            float4 mx;
            mx.x = fmaxf(hv.x, hn.x); mx.y = fmaxf(hv.y, hn.y);
            mx.z = fmaxf(hv.z, hn.z); mx.w = fmaxf(hv.w, hn.w);
            *outp = mx;
        }
    }
}

// ---------------------------------------------------------------- launch

extern "C" void kernel_launch(void* const* d_in, const int* in_sizes, int n_in,
                              void* d_out, int out_size, void* d_ws, size_t ws_size,
                              hipStream_t stream) {
    const float* x        = (const float*)d_in[0];          // [NN][FIN]
    const int*   ei       = (const int*)d_in[1];            // [2][NE]
    const float* ew       = (const float*)d_in[2];          // [NE]
    /* d_in[3] = numNode scalar = NN */
    const float* Wlin     = (const float*)d_in[4];          // [FIN][HD]
    const float* blin     = (const float*)d_in[5];          // [HD]
    const float* Wc       = (const float*)d_in[6];          // [3][HD][HD]
    const float* att_src  = (const float*)d_in[7];          // [3][HD]
    const float* att_dst  = (const float*)d_in[8];          // [3][HD]
    const float* bias_c   = (const float*)d_in[9];          // [3][HD]
    float* out = (float*)d_out;                              // [NN][HD]

    const int* src = ei;
    const int* dst = ei + NE;

    // workspace layout (16B-aligned blocks, ~52 MB)
    char* w = (char*)d_ws;
    float*  h       = (float*)w;   w += (size_t)NN * HD * 4;
    ushort* hpb     = (ushort*)w;  w += (size_t)NN * HD * 2;
    float*  as_     = (float*)w;   w += (size_t)NN * 4;
    float*  ad_     = (float*)w;   w += (size_t)NN * 4;
    int*    row_ptr = (int*)w;     w += (size_t)(NN + 4) * 4;
    int*    col     = (int*)w;     w += (size_t)NE * 4;
    float*  wsrt    = (float*)w;   w += (size_t)NE * 4;
    uint2*  epk     = (uint2*)w;   w += (size_t)NE * 8;
    int*    bhist   = (int*)w;     w += (size_t)NCH * NBK * 4;
    int*    bbeg    = (int*)w;     w += (size_t)(NBK + 4) * 4;
    ushort* WTh     = (ushort*)w;  w += (size_t)(HD * FIN + 3 * HD * HD) * 2;
    ushort* WTl     = (ushort*)w;  w += (size_t)(HD * FIN + 3 * HD * HD) * 2;
    ushort* WlinTh = WTh,            *WlinTl = WTl;
    ushort* WcTh   = WTh + HD * FIN, *WcTl   = WTl + HD * FIN;

    const int TB = 256;
    const int nblk_w = (NN * 64 + TB - 1) / TB;      // one wave per node
    const int nblk_g = (NN + 127) / 128;             // 391 (128 rows per block)

    // ---- weight transpose + split (tiny) ----
    k_split<<<(HD * FIN + TB - 1) / TB, TB, 0, stream>>>(Wlin, WlinTh, WlinTl, FIN);
    for (int l = 0; l < 3; ++l)
        k_split<<<(HD * HD + TB - 1) / TB, TB, 0, stream>>>(
            Wc + (size_t)l * HD * HD, WcTh + (size_t)l * HD * HD,
            WcTl + (size_t)l * HD * HD, HD);

    // ---- CSR build (atomic-reservation-free binning) ----
    k_bhist<<<NCH, 1024, 0, stream>>>(dst, bhist);
    k_bscan<<<1, 256, 0, stream>>>(bhist, bbeg, row_ptr);
    k_binscatter<<<NCH, 1024, 0, stream>>>(src, dst, ew, bhist, epk);
    k_build<<<NBK, 256, 0, stream>>>(epk, bbeg, row_ptr, col, wsrt);

    // ---- input projection: h = x @ Wlin + blin (fp32 out) ----
    k_gemm_mfma<FIN, false><<<nblk_g, TB, 0, stream>>>(
        x, WlinTh, WlinTl, blin, h, nullptr, nullptr, nullptr, nullptr, nullptr, NN);

    // ---- 3 GAT layers ----
    for (int layer = 0; layer < 3; ++layer) {
        k_gemm_mfma<HD, true><<<nblk_g, TB, 0, stream>>>(
            h, WcTh + (size_t)layer * HD * HD, WcTl + (size_t)layer * HD * HD,
            nullptr, nullptr, hpb,
            att_src + layer * HD, att_dst + layer * HD, as_, ad_, NN);
        int mode = (layer == 0) ? 0 : (layer == 2 ? 2 : 1);
        k_agg<<<nblk_w, TB, 0, stream>>>(hpb, h, as_, ad_, row_ptr, col, wsrt,
                                         bias_c + layer * HD, out, mode);
    }
}